// Round 7
// baseline (268.792 us; speedup 1.0000x reference)
//
#include <hip/hip_runtime.h>

#define BSZ   32768
#define H     512
#define K1DIM 532      // H + 20
#define KPAD  544      // padded to multiple of 32 (ws path)
#define ASTR  552      // LDS A row stride in shorts (2-way bank aliasing only)
#define BMS   64       // rows per block (R7: was 128 — 2 blocks/CU for phase overlap)
#define NBLKS (BSZ / BMS)  // 512 blocks == 2 per CU co-resident (74.9 KB LDS each)
#define CD    1024
#define NCATS 262144
#define LNEPS 1e-6f

typedef short bf16x8 __attribute__((ext_vector_type(8)));   // 8 bf16 in 4 VGPRs
typedef float f32x4  __attribute__((ext_vector_type(4)));

__device__ __forceinline__ unsigned short f2bf(float x) {
    unsigned int u = __float_as_uint(x);
    u += 0x7FFFu + ((u >> 16) & 1u);        // RNE
    return (unsigned short)(u >> 16);
}

__device__ __forceinline__ unsigned int pack_bf2(float lo, float hi) {
    return __builtin_amdgcn_perm(__float_as_uint(hi), __float_as_uint(lo), 0x07060302u);
}

// sum over 16 contiguous lanes via DPP only; full sum valid on ln==15 (R6-verified)
__device__ __forceinline__ float dpp_red16(float x) {
    x += __int_as_float(__builtin_amdgcn_update_dpp(0, __float_as_int(x), 0xB1, 0xf, 0xf, true)); // quad_perm [1,0,3,2]
    x += __int_as_float(__builtin_amdgcn_update_dpp(0, __float_as_int(x), 0x4E, 0xf, 0xf, true)); // quad_perm [2,3,0,1]
    x += __int_as_float(__builtin_amdgcn_update_dpp(0, __float_as_int(x), 0x114, 0xf, 0xf, true)); // row_shr:4
    x += __int_as_float(__builtin_amdgcn_update_dpp(0, __float_as_int(x), 0x118, 0xf, 0xf, true)); // row_shr:8
    return x;
}

// p-ary lower_bound over sorted cat_seg: 3 rounds of 64 probes (one wave) — R6-verified
__device__ __forceinline__ int psearch64(const int* __restrict__ seg, int target) {
    int lane = threadIdx.x & 63;
    int lo = 0, step = 4096;
    #pragma unroll
    for (int lvl = 0; lvl < 3; ++lvl) {
        int idx = lo + lane * step;
        bool lt = (idx < NCATS) && (seg[idx < NCATS ? idx : NCATS - 1] < target);
        unsigned long long m = __ballot(lt);
        int c = __popcll(m);
        if (c > 0) lo = lo + (c - 1) * step + 1;
        step >>= 6;
    }
    return lo;
}

__global__ void k_zero(unsigned int* __restrict__ flag) {
    if (threadIdx.x < 32) flag[threadIdx.x] = 0u;
}

// ======== R7: BM=64, 256-thread, 2-blocks/CU spin-barrier kernel ========
// R4/R6 evidence: kernel latency-bound (MfmaUtil <10%, VALUBusy <21%, HBM 3%) with
// one barrier-serialized 149.5KB-LDS block per CU. Split into two independent 74.9KB
// blocks per CU: same 8 waves/CU, but block A's barrier/memory stalls overlap block
// B's compute. Sync scheme unchanged (R4-verified): per-block release fence +
// atomicAdd arrival; pre-GEMM acquire spin (target NBLKS=512).
// Deadlock-safe: LDS 74.9KB*2<=160KB and __launch_bounds__(256,2) (<=256 VGPR)
// guarantee 2 blocks/CU => all 512 blocks co-resident; every block runs its prep
// prologue before any spin. Guard bound => pathological case fails absmax, not hangs.
__global__ __launch_bounds__(256, 2) void k_spin64(
    const float* __restrict__ encode, const float* __restrict__ credit,
    const float* __restrict__ meta_table, const float* __restrict__ conv_w,
    const float* __restrict__ conv_b,
    const float* __restrict__ w1f, const float* __restrict__ b1,
    const float* __restrict__ ln2_g, const float* __restrict__ ln2_b,
    const float* __restrict__ out_w, const float* __restrict__ out_b,
    const float* __restrict__ ln1_g, const float* __restrict__ ln1_b,
    const int* __restrict__ meta_ids, const int* __restrict__ cat_ids,
    const int* __restrict__ cat_seg, float* __restrict__ out,
    unsigned short* __restrict__ w1b, float* __restrict__ Gc,
    float* __restrict__ B0c, float* __restrict__ c0p, float* __restrict__ c1p,
    unsigned int* __restrict__ flag)
{
    __shared__ unsigned short Alds[BMS * ASTR];  // 70656 B
    __shared__ float Ssum[BMS][10];              // 2560 B [row][s,q,p0..5,pad,pad]
    __shared__ float cwL[90], cbL[5];
    __shared__ float sEnc[BMS], qEnc[BMS];       // stats, then mu/rs in place
    __shared__ float mu2[BMS], rs2[BMS];
    __shared__ float c0L[6], c1L[6];
    __shared__ int   startsL[BMS + 1];
    __shared__ int   sLoL, sHiL;

    const int tid  = threadIdx.x;
    const int row0 = blockIdx.x * BMS;
    const int lane = tid & 63;
    const int w    = tid >> 6;                   // wave 0..3

    // ---- Phase P: distributed ws prep across all 512 blocks
    {
        const int gt = blockIdx.x * 256 + tid;               // 0..131071
        for (int idx = gt; idx < CD * KPAD; idx += NBLKS * 256) {
            int row = idx / KPAD, k = idx - row * KPAD;
            float v = (k < K1DIM) ? w1f[(size_t)row * K1DIM + k] * ln1_g[k] : 0.f;
            w1b[idx] = f2bf(v);
        }
        if (w < 2) {                                         // G/B0: 2 cols per block
            int col = blockIdx.x * 2 + w;
            float g = 0.f, b = 0.f;
            for (int k = lane; k < K1DIM; k += 64) {
                float wv = w1f[(size_t)col * K1DIM + k];
                g = fmaf(ln1_g[k], wv, g);
                b = fmaf(ln1_b[k], wv, b);
            }
            #pragma unroll
            for (int m = 1; m < 64; m <<= 1) { g += __shfl_xor(g, m); b += __shfl_xor(b, m); }
            if (lane == 0) { Gc[col] = g; B0c[col] = b; }
        } else if (blockIdx.x < 3) {                         // c0/c1: blocks 0-2, waves 2,3
            int j = blockIdx.x * 2 + (w - 2);                // j = 0..5
            float s1 = 0.f, s0 = 0.f;
            for (int c = lane; c < CD; c += 64) {
                float wv = out_w[j * CD + c];
                s1 = fmaf(ln2_g[c], wv, s1);
                s0 = fmaf(ln2_b[c], wv, s0);
            }
            #pragma unroll
            for (int m = 1; m < 64; m <<= 1) { s1 += __shfl_xor(s1, m); s0 += __shfl_xor(s0, m); }
            if (lane == 0) { c1p[j] = s1; c0p[j] = s0 + out_b[j]; }
        }
    }
    __threadfence();                 // device-scope release of ws writes
    __syncthreads();
    if (tid == 0) atomicAdd(flag, 1u);   // arrival

    // ---- Phase A: boundary searches (waves 0,1) || constants (waves 2,3)
    if (w == 0) {
        int L = psearch64(cat_seg, row0);
        if (lane == 0) sLoL = L;
    } else if (w == 1) {
        int L = psearch64(cat_seg, row0 + BMS);
        if (lane == 0) sHiL = L;
    } else {
        const int t = tid - 128;
        if (t < 90) cwL[t] = conv_w[t];
        else if (t < 95) cbL[t - 90] = conv_b[t - 90];
        // c0L/c1L staged AFTER the spin barrier
    }
    for (int i = tid; i < BMS * 10; i += 256) ((float*)Ssum)[i] = 0.f;
    __syncthreads();

    // ---- Phase B: boundary scan + encode staging/stats (8 lanes/row, 32 rows/pass)
    {
        const int slo = sLoL, shi = sHiL;
        for (int i = slo - 1 + tid; i < shi; i += 256) {
            int a = (i >= 0) ? cat_seg[i] : -1;
            int b = (i + 1 < NCATS) ? cat_seg[i + 1] : BSZ;
            int rlo = max(a + 1, row0);
            int rhi = min(b, row0 + BMS);
            for (int r = rlo; r <= rhi; ++r) startsL[r - row0] = i + 1;
        }
    }
    #pragma unroll
    for (int rr = 0; rr < 2; ++rr) {
        const int r  = (tid >> 3) + rr * 32;
        const int cl = tid & 7;
        const float* erow = encode + (size_t)(row0 + r) * H;
        unsigned short* arow = Alds + r * ASTR;
        float s = 0.f, q = 0.f;
        #pragma unroll 4
        for (int i = 0; i < 16; i++) {
            int col = cl * 4 + i * 32;
            const float4 v = *(const float4*)(erow + col);
            s += v.x + v.y + v.z + v.w;
            q += v.x*v.x + v.y*v.y + v.z*v.z + v.w*v.w;
            ushort4 st = { f2bf(v.x), f2bf(v.y), f2bf(v.z), f2bf(v.w) };
            *(ushort4*)(arow + col) = st;
        }
        #pragma unroll
        for (int m = 1; m <= 4; m <<= 1) { s += __shfl_xor(s, m); q += __shfl_xor(q, m); }
        if (cl == 0) { sEnc[r] = s; qEnc[r] = q; }
    }
    __syncthreads();

    // ---- Phase C: meta gather + conv via in-wave shuffles (32 rows/pass)
    #pragma unroll 1
    for (int rr = 0; rr < 2; ++rr) {
        const int r = (tid >> 3) + rr * 32, k = tid & 7;
        const int s = startsL[r], e = startsL[r + 1];
        float val[8];
        #pragma unroll
        for (int d = 0; d < 8; d++) val[d] = 0.f;
        for (int i = s + k; i < e; i += 8) {
            int id = cat_ids[i];
            const float4 a = *(const float4*)(meta_table + (size_t)id * 8);
            const float4 b = *(const float4*)(meta_table + (size_t)id * 8 + 4);
            val[0] += a.x; val[1] += a.y; val[2] += a.z; val[3] += a.w;
            val[4] += b.x; val[5] += b.y; val[6] += b.z; val[7] += b.w;
        }
        #pragma unroll
        for (int m = 1; m <= 4; m <<= 1)
            #pragma unroll
            for (int d = 0; d < 8; d++) val[d] += __shfl_xor(val[d], m);
        float inv = 1.f / fmaxf((float)(e - s), 1.f);
        if (k == 0) {
            #pragma unroll
            for (int d = 0; d < 8; d++) val[d] *= inv;      // lane 0: avg_cat
        } else if (k <= 5) {
            int id = meta_ids[(size_t)(row0 + r) * 5 + (k - 1)];
            const float4 a = *(const float4*)(meta_table + (size_t)id * 8);
            const float4 b = *(const float4*)(meta_table + (size_t)id * 8 + 4);
            val[0] = a.x; val[1] = a.y; val[2] = a.z; val[3] = a.w;
            val[4] = b.x; val[5] = b.y; val[6] = b.z; val[7] = b.w;
        }
        const int base = lane & 56;
        float mm[6][8];
        #pragma unroll
        for (int src = 0; src < 6; src++)
            #pragma unroll
            for (int d = 0; d < 8; d++)
                mm[src][d] = __shfl(val[d], base + src);
        unsigned short* arow = Alds + r * ASTR;
        float s2 = 0.f, q2 = 0.f;
        if (k < 5) {                        // lane k computes conv output channel oc=k
            const int oc = k;
            float c[6];
            #pragma unroll
            for (int x = 0; x < 6; x++) {
                float a = cbL[oc];
                #pragma unroll
                for (int ic = 0; ic < 6; ic++)
                    #pragma unroll
                    for (int kj = 0; kj < 3; kj++)
                        a = fmaf(mm[ic][x + kj], cwL[(oc * 6 + ic) * 3 + kj], a);
                c[x] = fmaxf(a, 0.f);
            }
            unsigned short o[4];
            #pragma unroll
            for (int x = 0; x < 4; x++) {
                float p = fmaxf(fmaxf(c[x], c[x + 1]), c[x + 2]);
                s2 += p; q2 = fmaf(p, p, q2);
                o[x] = f2bf(p);
            }
            ushort4 st = { o[0], o[1], o[2], o[3] };
            *(ushort4*)(arow + 512 + oc * 4) = st;
        } else {                            // lanes 5,6,7: zero K-pad cols 532..543
            ushort4 z = { 0, 0, 0, 0 };
            *(ushort4*)(arow + 532 + (k - 5) * 4) = z;
        }
        #pragma unroll
        for (int m = 1; m <= 4; m <<= 1) { s2 += __shfl_xor(s2, m); q2 += __shfl_xor(q2, m); }
        if (k == 0) { sEnc[r] += s2; qEnc[r] += q2; }
    }
    __syncthreads();
    if (tid < BMS) {                        // finalize LN1 stats in place
        float mean = sEnc[tid] * (1.f / K1DIM);
        float var  = qEnc[tid] * (1.f / K1DIM) - mean * mean;
        sEnc[tid] = mean;
        qEnc[tid] = rsqrtf(var + LNEPS);
    }
    __syncthreads();

    // ---- spin barrier: all 512 blocks' prep complete before reading w1b
    if (tid == 0) {
        long long guard = 0;
        while (__hip_atomic_load(flag, __ATOMIC_RELAXED, __HIP_MEMORY_SCOPE_AGENT) < NBLKS
               && ++guard < (1LL << 27)) { }
    }
    __syncthreads();
    __threadfence();                 // acquire side

    // ---- GEMM1: 2 passes x 128 cols per wave, acc[4][8]=128; depth-2 A/B prefetch
    const int ln   = lane & 15;
    const int quad = lane >> 4;
    const unsigned short* aBase = Alds + ln * ASTR + quad * 8;

#define LDA4(A, kk) { _Pragma("unroll") for (int rt = 0; rt < 4; rt++) \
        A[rt] = *(const bf16x8*)(aBase + rt * 16 * ASTR + (kk) * 32); }
#define LDB8(Bv, kk) { _Pragma("unroll") for (int ct = 0; ct < 8; ct++) \
        Bv[ct] = *(const bf16x8*)(bp0 + (size_t)ct * 16 * KPAD + (kk) * 32); }
#define MFM(A, Bv) { _Pragma("unroll") for (int ct = 0; ct < 8; ct++) \
        _Pragma("unroll") for (int rt = 0; rt < 4; rt++) \
        acc[rt][ct] = __builtin_amdgcn_mfma_f32_16x16x32_bf16(A[rt], Bv[ct], acc[rt][ct], 0, 0, 0); }

    #pragma unroll 1
    for (int pass = 0; pass < 2; ++pass) {
        const int cb = pass * 512 + w * 128;
        const unsigned short* bp0 = w1b + (size_t)(cb + ln) * KPAD + quad * 8;

        f32x4 acc[4][8];
        #pragma unroll
        for (int rt = 0; rt < 4; rt++)
            #pragma unroll
            for (int ct = 0; ct < 8; ct++)
                acc[rt][ct] = f32x4{0.f, 0.f, 0.f, 0.f};

        bf16x8 bP[8], bQ[8], aF[4], aG[4];
        LDB8(bP, 0)
        LDB8(bQ, 1)
        #pragma unroll 1
        for (int kk = 0; kk < 16; kk += 2) {
            LDA4(aF, kk)
            MFM(aF, bP)
            LDB8(bP, kk + 2)                     // kk+2 <= 16: always valid
            LDA4(aG, kk + 1)
            MFM(aG, bQ)
            int k3 = (kk + 3 <= 16) ? kk + 3 : 1;
            LDB8(bQ, k3)
        }
        LDA4(aF, 16)
        MFM(aF, bP)

        // epilogue: h = relu(rs*(acc - mu*G) + B0 + b1); DPP-reduce; LDS atomic acc
        int colc[8]; float Gv[8], Bv[8], bv[8], vv[6][8];
        #pragma unroll
        for (int ct = 0; ct < 8; ct++) {
            colc[ct] = cb + ct * 16 + ln;
            Gv[ct] = Gc[colc[ct]]; Bv[ct] = B0c[colc[ct]]; bv[ct] = b1[colc[ct]];
            float g2 = ln2_g[colc[ct]];
            #pragma unroll
            for (int j = 0; j < 6; j++) vv[j][ct] = g2 * out_w[j * CD + colc[ct]];
        }
        #pragma unroll
        for (int rt = 0; rt < 4; rt++) {
            #pragma unroll
            for (int reg = 0; reg < 4; reg++) {
                const int row = rt * 16 + quad * 4 + reg;
                const float mu = sEnc[row], rs = qEnc[row];
                float s = 0.f, q = 0.f, p[6];
                #pragma unroll
                for (int j = 0; j < 6; j++) p[j] = 0.f;
                #pragma unroll
                for (int ct = 0; ct < 8; ct++) {
                    float h = fmaxf(rs * (acc[rt][ct][reg] - mu * Gv[ct]) + Bv[ct] + bv[ct], 0.f);
                    s += h; q = fmaf(h, h, q);
                    #pragma unroll
                    for (int j = 0; j < 6; j++) p[j] = fmaf(h, vv[j][ct], p[j]);
                }
                s = dpp_red16(s); q = dpp_red16(q);
                #pragma unroll
                for (int j = 0; j < 6; j++) p[j] = dpp_red16(p[j]);
                if (ln == 15) {
                    atomicAdd(&Ssum[row][0], s);
                    atomicAdd(&Ssum[row][1], q);
                    #pragma unroll
                    for (int j = 0; j < 6; j++) atomicAdd(&Ssum[row][2 + j], p[j]);
                }
            }
        }
    }
#undef LDA4
#undef LDB8
#undef MFM
    __syncthreads();

    if (tid < BMS) {
        float s = Ssum[tid][0], q = Ssum[tid][1];
        float mean = s * (1.f / CD);
        float var  = q * (1.f / CD) - mean * mean;
        mu2[tid] = mean; rs2[tid] = rsqrtf(var + LNEPS);
    } else if (tid < BMS + 6) {              // stage c0/c1 (produced in Phase P)
        c0L[tid - BMS] = c0p[tid - BMS];
    } else if (tid < BMS + 12) {
        c1L[tid - BMS - 6] = c1p[tid - BMS - 6];
    }
    __syncthreads();

    for (int t = tid; t < BMS * 6; t += 256) {
        int r = t / 6, j = t - r * 6;
        float S = Ssum[r][2 + j];
        int gr = row0 + r;
        float cs = 0.f;
        #pragma unroll
        for (int jj = 0; jj < 6; jj++) cs += credit[(size_t)gr * 6 + jj];
        float bias = (cs > 0.f) ? credit[(size_t)gr * 6 + j] / cs : (1.f / 6.f);
        out[(size_t)gr * 6 + j] = rs2[r] * S - mu2[r] * rs2[r] * c1L[j] + c0L[j] + bias;
    }
}

// ================= legacy fallback (no workspace) — R3-verified (BM=64) =================
__global__ __launch_bounds__(512, 2) void k_legacy(
    const float* __restrict__ encode, const float* __restrict__ credit,
    const float* __restrict__ meta_table, const float* __restrict__ conv_w,
    const float* __restrict__ conv_b, const float* __restrict__ ln1_g,
    const float* __restrict__ ln1_b, const float* __restrict__ w1f,
    const float* __restrict__ b1,
    const float* __restrict__ ln2_g, const float* __restrict__ ln2_b,
    const float* __restrict__ out_w, const float* __restrict__ out_b,
    const int* __restrict__ meta_ids, const int* __restrict__ cat_ids,
    const int* __restrict__ cat_seg, float* __restrict__ out)
{
    __shared__ unsigned short Alds[64 * ASTR];
    __shared__ float Vlds[6 * CD];
    __shared__ float gL[K1DIM], bL[K1DIM];
    __shared__ float cwL[90], cbL[5];
    __shared__ float mfL[64][20];
    __shared__ float sEnc[64], qEnc[64];
    __shared__ float muL[64], rsL[64];
    __shared__ float rowsum[64][8], rowsq[64][8];
    __shared__ float mu2[64], rs2[64];
    __shared__ float Sbuf[64][6][8];
    __shared__ float c0L[6], c1L[6];
    __shared__ int   startsL[65];
    __shared__ int   sLoL, sHiL;

    const int tid  = threadIdx.x;
    const int row0 = blockIdx.x * 64;
    const int lane = tid & 63;
    const int w    = tid >> 6;

    if (w == 0) {
        if (lane < 2) {
            int target = row0 + lane * 64;
            int lo = 0, hi = NCATS;
            while (lo < hi) { int mid = (lo + hi) >> 1; if (cat_seg[mid] < target) lo = mid + 1; else hi = mid; }
            if (lane == 0) sLoL = lo; else sHiL = lo;
        }
    } else {
        const int t = tid - 64;
        for (int i = t; i < 6 * CD; i += 448) Vlds[i] = ln2_g[i & (CD - 1)] * out_w[i];
        for (int i = t; i < K1DIM; i += 448) { gL[i] = ln1_g[i]; bL[i] = ln1_b[i]; }
        if (t < 90) cwL[t] = conv_w[t];
        if (t < 5)  cbL[t] = conv_b[t];
        for (int r = w - 1; r < 64; r += 7) {
            const float* p = encode + (size_t)(row0 + r) * H + lane * 8;
            float4 v0 = *(const float4*)p;
            float4 v1 = *(const float4*)(p + 4);
            float s = v0.x + v0.y + v0.z + v0.w + v1.x + v1.y + v1.z + v1.w;
            float q = v0.x*v0.x + v0.y*v0.y + v0.z*v0.z + v0.w*v0.w
                    + v1.x*v1.x + v1.y*v1.y + v1.z*v1.z + v1.w*v1.w;
            for (int m = 1; m < 64; m <<= 1) { s += __shfl_xor(s, m); q += __shfl_xor(q, m); }
            if (lane == 0) { sEnc[r] = s; qEnc[r] = q; }
        }
    }
    __syncthreads();

    {
        const int slo = sLoL, shi = sHiL;
        for (int i = slo - 1 + tid; i < shi; i += 512) {
            int a = (i >= 0) ? cat_seg[i] : -1;
            int b = (i + 1 < NCATS) ? cat_seg[i + 1] : BSZ;
            int rlo = max(a + 1, row0);
            int rhi = min(b, row0 + 64);
            for (int r = rlo; r <= rhi; ++r) startsL[r - row0] = i + 1;
        }
    }
    if (w >= 1 && w <= 6) {
        int j = w - 1;
        float s1 = 0.f, s0 = 0.f;
        for (int c = lane; c < CD; c += 64) {
            s1 += Vlds[j * CD + c];
            s0 = fmaf(ln2_b[c], out_w[j * CD + c], s0);
        }
        for (int m = 1; m < 64; m <<= 1) { s1 += __shfl_xor(s1, m); s0 += __shfl_xor(s0, m); }
        if (lane == 0) { c1L[j] = s1; c0L[j] = s0 + out_b[j]; }
    }
    __syncthreads();

    if (tid < 64) {
        const int r = tid;
        const int s = startsL[r], e = startsL[r + 1];
        float mm[6][8];
        float sum[8];
        #pragma unroll
        for (int d = 0; d < 8; d++) sum[d] = 0.f;
        for (int i = s; i < e; i++) {
            int id = cat_ids[i];
            const float4 a = *(const float4*)(meta_table + (size_t)id * 8);
            const float4 b = *(const float4*)(meta_table + (size_t)id * 8 + 4);
            sum[0] += a.x; sum[1] += a.y; sum[2] += a.z; sum[3] += a.w;
            sum[4] += b.x; sum[5] += b.y; sum[6] += b.z; sum[7] += b.w;
        }
        float cnt = fmaxf((float)(e - s), 1.f);
        #pragma unroll
        for (int d = 0; d < 8; d++) mm[0][d] = sum[d] / cnt;
        #pragma unroll
        for (int i = 0; i < 5; i++) {
            int id = meta_ids[(size_t)(row0 + r) * 5 + i];
            const float4 a = *(const float4*)(meta_table + (size_t)id * 8);
            const float4 b = *(const float4*)(meta_table + (size_t)id * 8 + 4);
            mm[1+i][0] = a.x; mm[1+i][1] = a.y; mm[1+i][2] = a.z; mm[1+i][3] = a.w;
            mm[1+i][4] = b.x; mm[1+i][5] = b.y; mm[1+i][6] = b.z; mm[1+i][7] = b.w;
        }
        float mfv[20];
        #pragma unroll
        for (int oc = 0; oc < 5; oc++) {
            float c[6];
            #pragma unroll
            for (int x = 0; x < 6; x++) {
                float a = cbL[oc];
                #pragma unroll
                for (int ic = 0; ic < 6; ic++)
                    #pragma unroll
                    for (int k = 0; k < 3; k++)
                        a = fmaf(mm[ic][x + k], cwL[(oc * 6 + ic) * 3 + k], a);
                c[x] = fmaxf(a, 0.f);
            }
            #pragma unroll
            for (int x = 0; x < 4; x++)
                mfv[oc * 4 + x] = fmaxf(fmaxf(c[x], c[x + 1]), c[x + 2]);
        }
        float sT = sEnc[r], qT = qEnc[r];
        #pragma unroll
        for (int j = 0; j < 20; j++) {
            mfL[r][j] = mfv[j];
            sT += mfv[j]; qT = fmaf(mfv[j], mfv[j], qT);
        }
        float mean = sT * (1.f / K1DIM);
        float var  = qT * (1.f / K1DIM) - mean * mean;
        muL[r] = mean;
        rsL[r] = rsqrtf(var + LNEPS);
    }
    __syncthreads();

    for (int i = tid; i < 64 * 136; i += 512) {
        int r = i / 136, c4 = i - r * 136;
        int col = c4 * 4;
        unsigned short o0 = 0, o1 = 0, o2 = 0, o3 = 0;
        if (c4 < 133) {
            float x0, x1, x2, x3;
            if (c4 < 128) {
                const float4 v = *(const float4*)&encode[(size_t)(row0 + r) * H + col];
                x0 = v.x; x1 = v.y; x2 = v.z; x3 = v.w;
            } else {
                int o = col - H;
                x0 = mfL[r][o]; x1 = mfL[r][o + 1]; x2 = mfL[r][o + 2]; x3 = mfL[r][o + 3];
            }
            float m = muL[r], rr = rsL[r];
            o0 = f2bf((x0 - m) * rr * gL[col + 0] + bL[col + 0]);
            o1 = f2bf((x1 - m) * rr * gL[col + 1] + bL[col + 1]);
            o2 = f2bf((x2 - m) * rr * gL[col + 2] + bL[col + 2]);
            o3 = f2bf((x3 - m) * rr * gL[col + 3] + bL[col + 3]);
        }
        ushort4 st = { o0, o1, o2, o3 };
        *(ushort4*)&Alds[r * ASTR + col] = st;
    }
    __syncthreads();

    const int ln   = lane & 15;
    const int quad = lane >> 4;
    const int cb   = w * 128;

    f32x4 acc[4][8];
    #pragma unroll
    for (int rt = 0; rt < 4; rt++)
        #pragma unroll
        for (int ct = 0; ct < 8; ct++)
            acc[rt][ct] = f32x4{0.f, 0.f, 0.f, 0.f};

    #pragma unroll 1
    for (int kk = 0; kk < 16; kk++) {
        bf16x8 af[4];
        #pragma unroll
        for (int rt = 0; rt < 4; rt++)
            af[rt] = *(const bf16x8*)&Alds[(rt * 16 + ln) * ASTR + kk * 32 + quad * 8];
        #pragma unroll
        for (int ct = 0; ct < 8; ct++) {
            const float* wrow = w1f + (size_t)(cb + ct * 16 + ln) * K1DIM + kk * 32 + quad * 8;
            const float4 fa = *(const float4*)wrow;
            const float4 fb = *(const float4*)(wrow + 4);
            union { bf16x8 v; unsigned int u[4]; } bu;
            bu.u[0] = pack_bf2(fa.x, fa.y);
            bu.u[1] = pack_bf2(fa.z, fa.w);
            bu.u[2] = pack_bf2(fb.x, fb.y);
            bu.u[3] = pack_bf2(fb.z, fb.w);
            #pragma unroll
            for (int rt = 0; rt < 4; rt++)
                acc[rt][ct] = __builtin_amdgcn_mfma_f32_16x16x32_bf16(af[rt], bu.v, acc[rt][ct], 0, 0, 0);
        }
    }
    {
        bf16x8 af[4];
        #pragma unroll
        for (int rt = 0; rt < 4; rt++)
            af[rt] = *(const bf16x8*)&Alds[(rt * 16 + ln) * ASTR + 512 + quad * 8];
        #pragma unroll
        for (int ct = 0; ct < 8; ct++) {
            union { bf16x8 v; unsigned int u[4]; } bu;
            bu.u[0] = 0; bu.u[1] = 0; bu.u[2] = 0; bu.u[3] = 0;
            const float* wrow = w1f + (size_t)(cb + ct * 16 + ln) * K1DIM + 512 + quad * 8;
            if (quad < 2) {
                const float4 fa = *(const float4*)wrow;
                const float4 fb = *(const float4*)(wrow + 4);
                bu.u[0] = pack_bf2(fa.x, fa.y);
                bu.u[1] = pack_bf2(fa.z, fa.w);
                bu.u[2] = pack_bf2(fb.x, fb.y);
                bu.u[3] = pack_bf2(fb.z, fb.w);
            } else if (quad == 2) {
                const float4 fa = *(const float4*)wrow;
                bu.u[0] = pack_bf2(fa.x, fa.y);
                bu.u[1] = pack_bf2(fa.z, fa.w);
            }
            #pragma unroll
            for (int rt = 0; rt < 4; rt++)
                acc[rt][ct] = __builtin_amdgcn_mfma_f32_16x16x32_bf16(af[rt], bu.v, acc[rt][ct], 0, 0, 0);
        }
    }

    float b1v[8]; int colc[8];
    #pragma unroll
    for (int ct = 0; ct < 8; ct++) { colc[ct] = cb + ct * 16 + ln; b1v[ct] = b1[colc[ct]]; }
    #pragma unroll
    for (int rt = 0; rt < 4; rt++)
        #pragma unroll
        for (int ct = 0; ct < 8; ct++)
            #pragma unroll
            for (int reg = 0; reg < 4; reg++)
                acc[rt][ct][reg] = fmaxf(acc[rt][ct][reg] + b1v[ct], 0.f);

    #pragma unroll
    for (int rt = 0; rt < 4; rt++) {
        #pragma unroll
        for (int reg = 0; reg < 4; reg++) {
            float s = 0.f, q = 0.f;
            #pragma unroll
            for (int ct = 0; ct < 8; ct++) { float f = acc[rt][ct][reg]; s += f; q = fmaf(f, f, q); }
            #pragma unroll
            for (int m = 1; m <= 8; m <<= 1) { s += __shfl_xor(s, m); q += __shfl_xor(q, m); }
            if (ln == 0) {
                int row = rt * 16 + quad * 4 + reg;
                rowsum[row][w] = s; rowsq[row][w] = q;
            }
        }
    }
    __syncthreads();
    if (tid < 64) {
        float s = 0.f, q = 0.f;
        #pragma unroll
        for (int ww = 0; ww < 8; ww++) { s += rowsum[tid][ww]; q += rowsq[tid][ww]; }
        float mean = s * (1.f / CD);
        float var  = q * (1.f / CD) - mean * mean;
        mu2[tid] = mean; rs2[tid] = rsqrtf(var + LNEPS);
    }

    float vv[6][8];
    #pragma unroll
    for (int j = 0; j < 6; j++)
        #pragma unroll
        for (int ct = 0; ct < 8; ct++)
            vv[j][ct] = Vlds[j * CD + colc[ct]];
    #pragma unroll
    for (int rt = 0; rt < 4; rt++) {
        #pragma unroll
        for (int reg = 0; reg < 4; reg++) {
            float p0 = 0.f, p1 = 0.f, p2 = 0.f, p3 = 0.f, p4 = 0.f, p5 = 0.f;
            #pragma unroll
            for (int ct = 0; ct < 8; ct++) {
                float f = acc[rt][ct][reg];
                p0 = fmaf(f, vv[0][ct], p0); p1 = fmaf(f, vv[1][ct], p1);
                p2 = fmaf(f, vv[2][ct], p2); p3 = fmaf(f, vv[3][ct], p3);
                p4 = fmaf(f, vv[4][ct], p4); p5 = fmaf(f, vv[5][ct], p5);
            }
            #pragma unroll
            for (int m = 1; m <= 8; m <<= 1) {
                p0 += __shfl_xor(p0, m); p1 += __shfl_xor(p1, m); p2 += __shfl_xor(p2, m);
                p3 += __shfl_xor(p3, m); p4 += __shfl_xor(p4, m); p5 += __shfl_xor(p5, m);
            }
            if (ln == 0) {
                int row = rt * 16 + quad * 4 + reg;
                Sbuf[row][0][w] = p0; Sbuf[row][1][w] = p1; Sbuf[row][2][w] = p2;
                Sbuf[row][3][w] = p3; Sbuf[row][4][w] = p4; Sbuf[row][5][w] = p5;
            }
        }
    }
    __syncthreads();

    if (tid < 384) {
        int r = tid / 6, j = tid - r * 6;
        float S = 0.f;
        #pragma unroll
        for (int ww = 0; ww < 8; ww++) S += Sbuf[r][j][ww];
        int gr = row0 + r;
        float cs = 0.f;
        #pragma unroll
        for (int jj = 0; jj < 6; jj++) cs += credit[(size_t)gr * 6 + jj];
        float bias = (cs > 0.f) ? credit[(size_t)gr * 6 + j] / cs : (1.f / 6.f);
        out[(size_t)gr * 6 + j] = rs2[r] * S - mu2[r] * rs2[r] * c1L[j] + c0L[j] + bias;
    }
}

extern "C" void kernel_launch(void* const* d_in, const int* in_sizes, int n_in,
                              void* d_out, int out_size, void* d_ws, size_t ws_size,
                              hipStream_t stream) {
    const float* encode     = (const float*)d_in[0];
    const float* credit     = (const float*)d_in[1];
    const float* meta_table = (const float*)d_in[2];
    const float* conv_w     = (const float*)d_in[3];
    const float* conv_b     = (const float*)d_in[4];
    const float* ln1_g      = (const float*)d_in[5];
    const float* ln1_b      = (const float*)d_in[6];
    const float* mlp1_w     = (const float*)d_in[7];
    const float* mlp1_b     = (const float*)d_in[8];
    const float* ln2_g      = (const float*)d_in[9];
    const float* ln2_b      = (const float*)d_in[10];
    const float* out_w      = (const float*)d_in[11];
    const float* out_b      = (const float*)d_in[12];
    const int*   meta_ids   = (const int*)d_in[13];
    const int*   cat_ids    = (const int*)d_in[14];
    const int*   cat_seg    = (const int*)d_in[15];
    float* out = (float*)d_out;

    // ws layout: w1b (g-folded bf16) | G | B0 | c0 | c1 | flag (128B-aligned)
    const size_t OFF_G    = (size_t)CD * KPAD * sizeof(unsigned short);   // 1,114,112
    const size_t OFF_B0   = OFF_G + CD * sizeof(float);
    const size_t OFF_C0   = OFF_B0 + CD * sizeof(float);
    const size_t OFF_C1   = OFF_C0 + 32;
    const size_t OFF_FLAG = (OFF_C1 + 32 + 127) & ~(size_t)127;           // 1,122,432
    const size_t WS_NEED  = OFF_FLAG + 128;                               // 1,122,560

    if (ws_size >= WS_NEED) {
        char* ws = (char*)d_ws;
        unsigned short* w1b = (unsigned short*)ws;
        float* G    = (float*)(ws + OFF_G);
        float* B0   = (float*)(ws + OFF_B0);
        float* c0   = (float*)(ws + OFF_C0);
        float* c1   = (float*)(ws + OFF_C1);
        unsigned int* flag = (unsigned int*)(ws + OFF_FLAG);

        k_zero<<<1, 64, 0, stream>>>(flag);
        k_spin64<<<NBLKS, 256, 0, stream>>>(
            encode, credit, meta_table, conv_w, conv_b,
            mlp1_w, mlp1_b, ln2_g, ln2_b, out_w, out_b, ln1_g, ln1_b,
            meta_ids, cat_ids, cat_seg, out,
            w1b, G, B0, c0, c1, flag);
    } else {
        k_legacy<<<BSZ / 64, 512, 0, stream>>>(
            encode, credit, meta_table, conv_w, conv_b, ln1_g, ln1_b,
            mlp1_w, mlp1_b, ln2_g, ln2_b, out_w, out_b,
            meta_ids, cat_ids, cat_seg, out);
    }
}